// Round 5
// baseline (384.839 us; speedup 1.0000x reference)
//
#include <hip/hip_runtime.h>

#define NNODES 100000
#define NEDGES 625000
#define DFEAT  128
#define NGRAPH 256
#define DOUTC  10

typedef __attribute__((ext_vector_type(8))) short bf16x8;
typedef __attribute__((ext_vector_type(4))) float f32x4;
typedef __attribute__((ext_vector_type(8))) ushort ushort8v;

__device__ __forceinline__ ushort f2bf(float f) {
    __bf16 b = (__bf16)f;
    return __builtin_bit_cast(ushort, b);
}
__device__ __forceinline__ float bf2f(ushort u) {
    return __builtin_bit_cast(float, (uint)u << 16);
}
__device__ __forceinline__ float bfhi2f(uint v) {
    return __builtin_bit_cast(float, v & 0xffff0000u);
}
__device__ __forceinline__ float bflo2f(uint v) {
    return __builtin_bit_cast(float, v << 16);
}

// ---------------------------------------------------------------------------
// CSR build: histogram -> scan -> scatter (counting sort of edges by row)
// ---------------------------------------------------------------------------
__global__ __launch_bounds__(256) void histo_kernel(const int* __restrict__ rows,
                                                    int* __restrict__ deg) {
    int i = blockIdx.x * 256 + threadIdx.x;
    if (i < NEDGES) atomicAdd(&deg[rows[i]], 1);
}

__global__ __launch_bounds__(256) void scan_block_sums(const int* __restrict__ deg,
                                                       int* __restrict__ bsum) {
    __shared__ int red[256];
    int b = blockIdx.x, t = threadIdx.x;
    int base = b * 1024 + t * 4;
    int s = 0;
#pragma unroll
    for (int j = 0; j < 4; ++j) {
        int i = base + j;
        if (i < NNODES) s += deg[i];
    }
    red[t] = s;
    __syncthreads();
    for (int off = 128; off > 0; off >>= 1) {
        if (t < off) red[t] += red[t + off];
        __syncthreads();
    }
    if (t == 0) bsum[b] = red[0];
}

__global__ __launch_bounds__(128) void scan_bsum(const int* __restrict__ bsum,
                                                 int* __restrict__ bbase, int nb) {
    __shared__ int sh[128];
    int t = threadIdx.x;
    sh[t] = (t < nb) ? bsum[t] : 0;
    __syncthreads();
    if (t == 0) {
        int run = 0;
        for (int i = 0; i < nb; ++i) { int v = sh[i]; sh[i] = run; run += v; }
    }
    __syncthreads();
    if (t < nb) bbase[t] = sh[t];
}

__global__ __launch_bounds__(256) void scan_write(const int* __restrict__ deg,
                                                  const int* __restrict__ bbase,
                                                  int* __restrict__ offs,
                                                  int* __restrict__ cursor) {
    __shared__ int red[256];
    int b = blockIdx.x, t = threadIdx.x;
    int base = b * 1024 + t * 4;
    int v[4];
    int s = 0;
#pragma unroll
    for (int j = 0; j < 4; ++j) {
        int i = base + j;
        v[j] = (i < NNODES) ? deg[i] : 0;
        s += v[j];
    }
    red[t] = s;
    __syncthreads();
    int x = s;
    for (int off = 1; off < 256; off <<= 1) {
        int y = (t >= off) ? red[t - off] : 0;
        __syncthreads();
        x += y;
        red[t] = x;
        __syncthreads();
    }
    int pre = bbase[b] + x - s;
#pragma unroll
    for (int j = 0; j < 4; ++j) {
        int i = base + j;
        if (i < NNODES) { offs[i] = pre; cursor[i] = pre; }
        pre += v[j];
    }
    if (b == gridDim.x - 1 && t == 255) offs[NNODES] = bbase[b] + x;
}

__global__ __launch_bounds__(256) void scatter_edges(const int* __restrict__ rows,
                                                     const int* __restrict__ cols,
                                                     int* __restrict__ cursor,
                                                     int* __restrict__ scol) {
    int i = blockIdx.x * 256 + threadIdx.x;
    if (i < NEDGES) {
        int p = atomicAdd(&cursor[rows[i]], 1);
        scol[p] = cols[i];
    }
}

// ---------------------------------------------------------------------------
// dtype conversion
// ---------------------------------------------------------------------------
__global__ __launch_bounds__(256) void convert_x_bf16(const float* __restrict__ src,
                                                      ushort* __restrict__ dst) {
    int i = blockIdx.x * 256 + threadIdx.x;
    const int n8 = NNODES * DFEAT / 8;
    if (i >= n8) return;
    float4 a = *(const float4*)&src[(size_t)i * 8];
    float4 b = *(const float4*)&src[(size_t)i * 8 + 4];
    ushort8v o;
    o[0] = f2bf(a.x); o[1] = f2bf(a.y); o[2] = f2bf(a.z); o[3] = f2bf(a.w);
    o[4] = f2bf(b.x); o[5] = f2bf(b.y); o[6] = f2bf(b.z); o[7] = f2bf(b.w);
    *(ushort8v*)&dst[(size_t)i * 8] = o;
}

__global__ __launch_bounds__(256) void convert_weights(const float* __restrict__ w0,
                                                       const float* __restrict__ w1,
                                                       const float* __restrict__ w2,
                                                       const float* __restrict__ w3,
                                                       const float* __restrict__ w4,
                                                       const float* __restrict__ w5,
                                                       ushort* __restrict__ dst) {
    int i = blockIdx.x * 256 + threadIdx.x;
    if (i >= 6 * DFEAT * DFEAT) return;
    const float* ptrs[6] = {w0, w1, w2, w3, w4, w5};
    int m = i >> 14, j = i & 16383;
    dst[i] = f2bf(ptrs[m][j]);
}

// ---------------------------------------------------------------------------
// Dual GEMM, wave-pair structure: within each block, waves {0,1} / {2,3} form
// pairs processing the SAME 16-node tile; even wave -> W1/S, odd wave -> W2/Y.
// The pair's H-fragment loads are temporally adjacent on one CU -> the second
// load hits L1/L2, so H is fetched from HBM once (77 MB streaming total).
// Weights live in 128 VGPRs per wave (L2-broadcast across waves).
// ---------------------------------------------------------------------------
__global__ __launch_bounds__(256, 2) void dual_gemm_pairs(const ushort* __restrict__ Hb,
                                                          const ushort* __restrict__ W1b,
                                                          const ushort* __restrict__ W2b,
                                                          ushort* __restrict__ Sb,
                                                          ushort* __restrict__ Yb) {
    int wid = threadIdx.x >> 6;              // 0..3
    int lane = threadIdx.x & 63;
    int l15 = lane & 15, lhi = lane >> 4;
    int mat = wid & 1;
    const ushort* __restrict__ W = mat ? W2b : W1b;
    ushort* __restrict__ O = mat ? Yb : Sb;

    // all 32 weight fragments once: outs [ot*16,ot*16+16), k [ks*32,ks*32+32)
    bf16x8 w[8][4];
#pragma unroll
    for (int ot = 0; ot < 8; ++ot)
#pragma unroll
        for (int ks = 0; ks < 4; ++ks)
            w[ot][ks] = *(const bf16x8*)&W[(ot * 16 + l15) * DFEAT + ks * 32 + lhi * 8];

    int pair = blockIdx.x * 2 + (wid >> 1);
    const int npairs = gridDim.x * 2;
    const int ntiles = NNODES / 16;          // 6250 exactly

    for (int t = pair; t < ntiles; t += npairs) {
        int nodeBase = t * 16;
        size_t rowOff = (size_t)(nodeBase + l15) * DFEAT;
        bf16x8 hfr[4];
#pragma unroll
        for (int ks = 0; ks < 4; ++ks)
            hfr[ks] = *(const bf16x8*)&Hb[rowOff + ks * 32 + lhi * 8];
        f32x4 acc[8];
#pragma unroll
        for (int ot = 0; ot < 8; ++ot) {
            f32x4 a = {};
#pragma unroll
            for (int ks = 0; ks < 4; ++ks)
                a = __builtin_amdgcn_mfma_f32_16x16x32_bf16(w[ot][ks], hfr[ks], a, 0, 0, 0);
            acc[ot] = a;
        }
#pragma unroll
        for (int ot = 0; ot < 8; ++ot) {
            f32x4 a = acc[ot];
            ushort4 p;
            p.x = f2bf(a.x); p.y = f2bf(a.y); p.z = f2bf(a.z); p.w = f2bf(a.w);
            *(ushort4*)&O[rowOff + ot * 16 + lhi * 4] = p;
        }
    }
}

// ---------------------------------------------------------------------------
// Aggregate + ReLU (bf16 in/out, f32 accumulate). One wave per node.
// scol software-pipelined (next 4 indices prefetched while 4 gathers fly);
// nontemporal on the read-once S stream and write-once H stream to keep
// L2 capacity for Y-row gather reuse.
// ---------------------------------------------------------------------------
__global__ __launch_bounds__(256) void aggregate_relu_bf16(const ushort* __restrict__ Sb,
                                                           const ushort* __restrict__ Yb,
                                                           const int* __restrict__ offs,
                                                           const int* __restrict__ scol,
                                                           ushort* __restrict__ Hout) {
    int node = (blockIdx.x * 256 + threadIdx.x) >> 6;
    int lane = threadIdx.x & 63;
    if (node >= NNODES) return;
    int beg = offs[node];
    int end = offs[node + 1];
    const uint* Yp = (const uint*)Yb + lane;
    float ax = 0.f, ay = 0.f;
    int e = beg;
    if (e + 4 <= end) {
        int c0 = scol[e], c1 = scol[e + 1], c2 = scol[e + 2], c3 = scol[e + 3];
        for (;;) {
            uint v0 = Yp[c0 * 64];
            uint v1 = Yp[c1 * 64];
            uint v2 = Yp[c2 * 64];
            uint v3 = Yp[c3 * 64];
            e += 4;
            bool more = (e + 4 <= end);
            int n0, n1, n2, n3;
            if (more) {
                n0 = scol[e]; n1 = scol[e + 1]; n2 = scol[e + 2]; n3 = scol[e + 3];
            }
            ax += (bflo2f(v0) + bflo2f(v1)) + (bflo2f(v2) + bflo2f(v3));
            ay += (bfhi2f(v0) + bfhi2f(v1)) + (bfhi2f(v2) + bfhi2f(v3));
            if (!more) break;
            c0 = n0; c1 = n1; c2 = n2; c3 = n3;
        }
    }
    for (; e < end; ++e) {
        uint v0 = Yp[scol[e] * 64];
        ax += bflo2f(v0);
        ay += bfhi2f(v0);
    }
    uint sv = __builtin_nontemporal_load((const uint*)Sb + (size_t)node * 64 + lane);
    float hx = fmaxf(bflo2f(sv) + ax, 0.f);
    float hy = fmaxf(bfhi2f(sv) + ay, 0.f);
    uint packed = (uint)f2bf(hx) | ((uint)f2bf(hy) << 16);
    __builtin_nontemporal_store(packed, (uint*)Hout + (size_t)node * 64 + lane);
}

// ---------------------------------------------------------------------------
// Pooling phase 1: per-graph feature sums (run-accumulate over sorted batch).
// ---------------------------------------------------------------------------
__global__ __launch_bounds__(256) void pool_partial(const ushort* __restrict__ Hb,
                                                    const int* __restrict__ batch,
                                                    float* __restrict__ gsum) {
    int wave = (blockIdx.x * 256 + threadIdx.x) >> 6;
    int lane = threadIdx.x & 63;
    int base = wave * 64;
    if (base >= NNODES) return;
    int end = min(base + 64, NNODES);
    const uint* Hp = (const uint*)Hb + lane;
    float ax = 0.f, ay = 0.f;
    int gprev = batch[base];
    for (int n = base; n < end; ++n) {
        int g = batch[n];
        if (g != gprev) {
            atomicAdd(&gsum[gprev * DFEAT + lane * 2], ax);
            atomicAdd(&gsum[gprev * DFEAT + lane * 2 + 1], ay);
            ax = 0.f; ay = 0.f; gprev = g;
        }
        uint v = Hp[(size_t)n * 64];
        ax += bflo2f(v);
        ay += bfhi2f(v);
    }
    atomicAdd(&gsum[gprev * DFEAT + lane * 2], ax);
    atomicAdd(&gsum[gprev * DFEAT + lane * 2 + 1], ay);
}

// ---------------------------------------------------------------------------
// Pooling phase 2: divide by count, classify.
// ---------------------------------------------------------------------------
__global__ __launch_bounds__(128) void pool_classify2(const float* __restrict__ gsum,
                                                      const int* __restrict__ batch,
                                                      const float* __restrict__ Wc,
                                                      const float* __restrict__ bc,
                                                      float* __restrict__ out) {
    int g = blockIdx.x;
    int f = threadIdx.x;
    __shared__ int bounds[2];
    if (f < 2) {
        int target = g + f;
        int lo = 0, hi = NNODES;
        while (lo < hi) {
            int mid = (lo + hi) >> 1;
            if (batch[mid] < target) lo = mid + 1; else hi = mid;
        }
        bounds[f] = lo;
    }
    __syncthreads();
    float cnt = (float)(bounds[1] - bounds[0]);
    float pooled = gsum[g * DFEAT + f] / fmaxf(cnt, 1.0f);

    __shared__ float red[128];
    for (int o = 0; o < DOUTC; ++o) {
        red[f] = pooled * Wc[o * DFEAT + f];
        __syncthreads();
        for (int off = 64; off > 0; off >>= 1) {
            if (f < off) red[f] += red[f + off];
            __syncthreads();
        }
        if (f == 0) out[g * DOUTC + o] = red[0] + bc[o];
        __syncthreads();
    }
}

// ---------------------------------------------------------------------------
extern "C" void kernel_launch(void* const* d_in, const int* in_sizes, int n_in,
                              void* d_out, int out_size, void* d_ws, size_t ws_size,
                              hipStream_t stream) {
    const float* x    = (const float*)d_in[0];
    const int*   ei   = (const int*)d_in[1];
    const int*   batch= (const int*)d_in[2];
    const float* W1_0 = (const float*)d_in[3];
    const float* W2_0 = (const float*)d_in[4];
    const float* W1_1 = (const float*)d_in[5];
    const float* W2_1 = (const float*)d_in[6];
    const float* W1_2 = (const float*)d_in[7];
    const float* W2_2 = (const float*)d_in[8];
    const float* Wc   = (const float*)d_in[9];
    const float* bc   = (const float*)d_in[10];
    float* out = (float*)d_out;

    const int* rows = ei;            // edge_index[0] = dst (segment)
    const int* cols = ei + NEDGES;   // edge_index[1] = src (gather)

    // workspace carve-up
    char* ws = (char*)d_ws;
    ushort* Hb = (ushort*)ws;  ws += (size_t)NNODES * DFEAT * sizeof(ushort);
    ushort* Sb = (ushort*)ws;  ws += (size_t)NNODES * DFEAT * sizeof(ushort);
    ushort* Yb = (ushort*)ws;  ws += (size_t)NNODES * DFEAT * sizeof(ushort);
    ushort* Wb = (ushort*)ws;  ws += (size_t)6 * DFEAT * DFEAT * sizeof(ushort);
    float* gsum = (float*)ws;  ws += (size_t)NGRAPH * DFEAT * sizeof(float);
    int* deg    = (int*)ws;    ws += (size_t)NNODES * sizeof(int);
    int* offs   = (int*)ws;    ws += (size_t)(NNODES + 1) * sizeof(int);
    int* cursor = (int*)ws;    ws += (size_t)NNODES * sizeof(int);
    int* scol   = (int*)ws;    ws += (size_t)NEDGES * sizeof(int);
    int* bsum   = (int*)ws;    ws += 128 * sizeof(int);
    int* bbase  = (int*)ws;    ws += 128 * sizeof(int);

    const int NB = (NNODES + 1023) / 1024;

    // dtype conversion
    convert_weights<<<(6 * DFEAT * DFEAT + 255) / 256, 256, 0, stream>>>(
        W1_0, W2_0, W1_1, W2_1, W1_2, W2_2, Wb);
    convert_x_bf16<<<(NNODES * DFEAT / 8 + 255) / 256, 256, 0, stream>>>(x, Hb);

    // CSR build
    hipMemsetAsync(deg, 0, (size_t)NNODES * sizeof(int), stream);
    hipMemsetAsync(gsum, 0, (size_t)NGRAPH * DFEAT * sizeof(float), stream);
    histo_kernel<<<(NEDGES + 255) / 256, 256, 0, stream>>>(rows, deg);
    scan_block_sums<<<NB, 256, 0, stream>>>(deg, bsum);
    scan_bsum<<<1, 128, 0, stream>>>(bsum, bbase, NB);
    scan_write<<<NB, 256, 0, stream>>>(deg, bbase, offs, cursor);
    scatter_edges<<<(NEDGES + 255) / 256, 256, 0, stream>>>(rows, cols, cursor, scol);

    // 3 GNN layers
    const int gemmGrid = 784;                        // 1568 wave-pairs, ~4 tiles each
    const int aggGrid  = ((size_t)NNODES * 64 + 255) / 256;
    for (int l = 0; l < 3; ++l) {
        const ushort* w1 = Wb + (size_t)(2 * l) * DFEAT * DFEAT;
        const ushort* w2 = Wb + (size_t)(2 * l + 1) * DFEAT * DFEAT;
        dual_gemm_pairs<<<gemmGrid, 256, 0, stream>>>(Hb, w1, w2, Sb, Yb);
        aggregate_relu_bf16<<<aggGrid, 256, 0, stream>>>(Sb, Yb, offs, scol, Hb);
    }

    // pooling + classifier
    const int poolWaves = (NNODES + 63) / 64;
    pool_partial<<<(poolWaves * 64 + 255) / 256, 256, 0, stream>>>(Hb, batch, gsum);
    pool_classify2<<<NGRAPH, 128, 0, stream>>>(gsum, batch, Wc, bc, out);
}

// Round 6
// 344.647 us; speedup vs baseline: 1.1166x; 1.1166x over previous
//
#include <hip/hip_runtime.h>

#define NNODES 100000
#define NEDGES 625000
#define DFEAT  128
#define NGRAPH 256
#define DOUTC  10

typedef __attribute__((ext_vector_type(8))) short bf16x8;
typedef __attribute__((ext_vector_type(4))) float f32x4;
typedef __attribute__((ext_vector_type(8))) ushort ushort8v;

__device__ __forceinline__ ushort f2bf(float f) {
    __bf16 b = (__bf16)f;
    return __builtin_bit_cast(ushort, b);
}
__device__ __forceinline__ float bf2f(ushort u) {
    return __builtin_bit_cast(float, (uint)u << 16);
}

// ---------------------------------------------------------------------------
// CSR build: histogram -> scan -> scatter (counting sort of edges by row)
// ---------------------------------------------------------------------------
__global__ __launch_bounds__(256) void histo_kernel(const int* __restrict__ rows,
                                                    int* __restrict__ deg) {
    int i = blockIdx.x * 256 + threadIdx.x;
    if (i < NEDGES) atomicAdd(&deg[rows[i]], 1);
}

__global__ __launch_bounds__(256) void scan_block_sums(const int* __restrict__ deg,
                                                       int* __restrict__ bsum) {
    __shared__ int red[256];
    int b = blockIdx.x, t = threadIdx.x;
    int base = b * 1024 + t * 4;
    int s = 0;
#pragma unroll
    for (int j = 0; j < 4; ++j) {
        int i = base + j;
        if (i < NNODES) s += deg[i];
    }
    red[t] = s;
    __syncthreads();
    for (int off = 128; off > 0; off >>= 1) {
        if (t < off) red[t] += red[t + off];
        __syncthreads();
    }
    if (t == 0) bsum[b] = red[0];
}

__global__ __launch_bounds__(128) void scan_bsum(const int* __restrict__ bsum,
                                                 int* __restrict__ bbase, int nb) {
    __shared__ int sh[128];
    int t = threadIdx.x;
    sh[t] = (t < nb) ? bsum[t] : 0;
    __syncthreads();
    if (t == 0) {
        int run = 0;
        for (int i = 0; i < nb; ++i) { int v = sh[i]; sh[i] = run; run += v; }
    }
    __syncthreads();
    if (t < nb) bbase[t] = sh[t];
}

__global__ __launch_bounds__(256) void scan_write(const int* __restrict__ deg,
                                                  const int* __restrict__ bbase,
                                                  int* __restrict__ offs,
                                                  int* __restrict__ cursor) {
    __shared__ int red[256];
    int b = blockIdx.x, t = threadIdx.x;
    int base = b * 1024 + t * 4;
    int v[4];
    int s = 0;
#pragma unroll
    for (int j = 0; j < 4; ++j) {
        int i = base + j;
        v[j] = (i < NNODES) ? deg[i] : 0;
        s += v[j];
    }
    red[t] = s;
    __syncthreads();
    int x = s;
    for (int off = 1; off < 256; off <<= 1) {
        int y = (t >= off) ? red[t - off] : 0;
        __syncthreads();
        x += y;
        red[t] = x;
        __syncthreads();
    }
    int pre = bbase[b] + x - s;
#pragma unroll
    for (int j = 0; j < 4; ++j) {
        int i = base + j;
        if (i < NNODES) { offs[i] = pre; cursor[i] = pre; }
        pre += v[j];
    }
    if (b == gridDim.x - 1 && t == 255) offs[NNODES] = bbase[b] + x;
}

__global__ __launch_bounds__(256) void scatter_edges(const int* __restrict__ rows,
                                                     const int* __restrict__ cols,
                                                     int* __restrict__ cursor,
                                                     int* __restrict__ scol) {
    int i = blockIdx.x * 256 + threadIdx.x;
    if (i < NEDGES) {
        int p = atomicAdd(&cursor[rows[i]], 1);
        scol[p] = cols[i];
    }
}

// ---------------------------------------------------------------------------
// dtype conversion
// ---------------------------------------------------------------------------
__global__ __launch_bounds__(256) void convert_x_bf16(const float* __restrict__ src,
                                                      ushort* __restrict__ dst) {
    int i = blockIdx.x * 256 + threadIdx.x;
    const int n8 = NNODES * DFEAT / 8;
    if (i >= n8) return;
    float4 a = *(const float4*)&src[(size_t)i * 8];
    float4 b = *(const float4*)&src[(size_t)i * 8 + 4];
    ushort8v o;
    o[0] = f2bf(a.x); o[1] = f2bf(a.y); o[2] = f2bf(a.z); o[3] = f2bf(a.w);
    o[4] = f2bf(b.x); o[5] = f2bf(b.y); o[6] = f2bf(b.z); o[7] = f2bf(b.w);
    *(ushort8v*)&dst[(size_t)i * 8] = o;
}

__global__ __launch_bounds__(256) void convert_weights(const float* __restrict__ w0,
                                                       const float* __restrict__ w1,
                                                       const float* __restrict__ w2,
                                                       const float* __restrict__ w3,
                                                       const float* __restrict__ w4,
                                                       const float* __restrict__ w5,
                                                       ushort* __restrict__ dst) {
    int i = blockIdx.x * 256 + threadIdx.x;
    if (i >= 6 * DFEAT * DFEAT) return;
    const float* ptrs[6] = {w0, w1, w2, w3, w4, w5};
    int m = i >> 14, j = i & 16383;
    dst[i] = f2bf(ptrs[m][j]);
}

// ---------------------------------------------------------------------------
// Aggregate in H-space: A[n] = sum_{e in CSR[n]} H[scol[e]]   (bf16->f32->bf16)
// One wave per node. Lane-group g (16 lanes) handles edge e+g; each lane
// reads 16 B (8 bf16 feats) -> one dwordx4 load gathers 4 full edge rows.
// Two loads in flight (8 edges). Final 2-step shfl_xor butterfly merges the
// 4 group accumulators; lanes 0-15 store the 256 B row.
// ---------------------------------------------------------------------------
__global__ __launch_bounds__(256) void aggregate_gather4(const ushort* __restrict__ Hb,
                                                         const int* __restrict__ offs,
                                                         const int* __restrict__ scol,
                                                         ushort* __restrict__ Ab) {
    int node = (blockIdx.x * 256 + threadIdx.x) >> 6;
    int lane = threadIdx.x & 63;
    if (node >= NNODES) return;
    int g = lane >> 4;          // edge slot 0..3
    int l = lane & 15;          // feature chunk (8 feats)
    int beg = offs[node];
    int end = offs[node + 1];
    float a[8] = {};
    for (int e = beg; e < end; e += 8) {
        int i0 = e + g;
        int i1 = e + 4 + g;
        int c0 = scol[min(i0, end - 1)];
        int c1 = scol[min(i1, end - 1)];
        ushort8v v0 = *(const ushort8v*)&Hb[(size_t)c0 * DFEAT + l * 8];
        ushort8v v1 = *(const ushort8v*)&Hb[(size_t)c1 * DFEAT + l * 8];
        if (i0 < end) {
#pragma unroll
            for (int j = 0; j < 8; ++j) a[j] += bf2f(v0[j]);
        }
        if (i1 < end) {
#pragma unroll
            for (int j = 0; j < 8; ++j) a[j] += bf2f(v1[j]);
        }
    }
#pragma unroll
    for (int j = 0; j < 8; ++j) {
        a[j] += __shfl_xor(a[j], 16, 64);
        a[j] += __shfl_xor(a[j], 32, 64);
    }
    if (lane < 16) {
        ushort8v o;
#pragma unroll
        for (int j = 0; j < 8; ++j) o[j] = f2bf(a[j]);
        *(ushort8v*)&Ab[(size_t)node * DFEAT + l * 8] = o;
    }
}

// ---------------------------------------------------------------------------
// Fused layer GEMM: H' = relu(H @ W1^T + A @ W2^T)  (bf16 in/out, f32 acc).
// Wave handles out-half (wid&1): holds W1,W2 fragments for 64 out-features
// (128 VGPR). Teams of 2 waves share each 16-node tile (L1/L2 locality).
// Both matmuls accumulate into the SAME MFMA accumulator.
// ---------------------------------------------------------------------------
__global__ __launch_bounds__(256, 2) void fused_dual_gemm(const ushort* __restrict__ Hin,
                                                          const ushort* __restrict__ Ab,
                                                          const ushort* __restrict__ W1b,
                                                          const ushort* __restrict__ W2b,
                                                          ushort* __restrict__ Hout) {
    int wid = threadIdx.x >> 6;
    int lane = threadIdx.x & 63;
    int l15 = lane & 15, lhi = lane >> 4;
    int half = wid & 1;

    // weight fragments for this half's 64 out-features
    bf16x8 w1[4][4], w2[4][4];
#pragma unroll
    for (int ot = 0; ot < 4; ++ot)
#pragma unroll
        for (int ks = 0; ks < 4; ++ks) {
            int orow = half * 64 + ot * 16 + l15;
            w1[ot][ks] = *(const bf16x8*)&W1b[orow * DFEAT + ks * 32 + lhi * 8];
            w2[ot][ks] = *(const bf16x8*)&W2b[orow * DFEAT + ks * 32 + lhi * 8];
        }

    int team = blockIdx.x * 2 + (wid >> 1);
    const int nteams = gridDim.x * 2;
    const int ntiles = NNODES / 16;              // 6250 exactly

    for (int t = team; t < ntiles; t += nteams) {
        size_t rowOff = (size_t)(t * 16 + l15) * DFEAT;
        bf16x8 hfr[4], afr[4];
#pragma unroll
        for (int ks = 0; ks < 4; ++ks) {
            hfr[ks] = *(const bf16x8*)&Hin[rowOff + ks * 32 + lhi * 8];
            afr[ks] = *(const bf16x8*)&Ab[rowOff + ks * 32 + lhi * 8];
        }
#pragma unroll
        for (int ot = 0; ot < 4; ++ot) {
            f32x4 acc = {};
#pragma unroll
            for (int ks = 0; ks < 4; ++ks)
                acc = __builtin_amdgcn_mfma_f32_16x16x32_bf16(w1[ot][ks], hfr[ks], acc, 0, 0, 0);
#pragma unroll
            for (int ks = 0; ks < 4; ++ks)
                acc = __builtin_amdgcn_mfma_f32_16x16x32_bf16(w2[ot][ks], afr[ks], acc, 0, 0, 0);
            ushort4 p;
            p.x = f2bf(fmaxf(acc.x, 0.f));
            p.y = f2bf(fmaxf(acc.y, 0.f));
            p.z = f2bf(fmaxf(acc.z, 0.f));
            p.w = f2bf(fmaxf(acc.w, 0.f));
            *(ushort4*)&Hout[rowOff + half * 64 + ot * 16 + lhi * 4] = p;
        }
    }
}

// ---------------------------------------------------------------------------
// Pooling phase 1: per-graph feature sums (run-accumulate over sorted batch).
// ---------------------------------------------------------------------------
__global__ __launch_bounds__(256) void pool_partial(const ushort* __restrict__ Hb,
                                                    const int* __restrict__ batch,
                                                    float* __restrict__ gsum) {
    int wave = (blockIdx.x * 256 + threadIdx.x) >> 6;
    int lane = threadIdx.x & 63;
    int base = wave * 64;
    if (base >= NNODES) return;
    int end = min(base + 64, NNODES);
    const uint* Hp = (const uint*)Hb + lane;
    float ax = 0.f, ay = 0.f;
    int gprev = batch[base];
    for (int n = base; n < end; ++n) {
        int g = batch[n];
        if (g != gprev) {
            atomicAdd(&gsum[gprev * DFEAT + lane * 2], ax);
            atomicAdd(&gsum[gprev * DFEAT + lane * 2 + 1], ay);
            ax = 0.f; ay = 0.f; gprev = g;
        }
        uint v = Hp[(size_t)n * 64];
        ax += __builtin_bit_cast(float, v << 16);
        ay += __builtin_bit_cast(float, v & 0xffff0000u);
    }
    atomicAdd(&gsum[gprev * DFEAT + lane * 2], ax);
    atomicAdd(&gsum[gprev * DFEAT + lane * 2 + 1], ay);
}

// ---------------------------------------------------------------------------
// Pooling phase 2: divide by count, classify.
// ---------------------------------------------------------------------------
__global__ __launch_bounds__(128) void pool_classify2(const float* __restrict__ gsum,
                                                      const int* __restrict__ batch,
                                                      const float* __restrict__ Wc,
                                                      const float* __restrict__ bc,
                                                      float* __restrict__ out) {
    int g = blockIdx.x;
    int f = threadIdx.x;
    __shared__ int bounds[2];
    if (f < 2) {
        int target = g + f;
        int lo = 0, hi = NNODES;
        while (lo < hi) {
            int mid = (lo + hi) >> 1;
            if (batch[mid] < target) lo = mid + 1; else hi = mid;
        }
        bounds[f] = lo;
    }
    __syncthreads();
    float cnt = (float)(bounds[1] - bounds[0]);
    float pooled = gsum[g * DFEAT + f] / fmaxf(cnt, 1.0f);

    __shared__ float red[128];
    for (int o = 0; o < DOUTC; ++o) {
        red[f] = pooled * Wc[o * DFEAT + f];
        __syncthreads();
        for (int off = 64; off > 0; off >>= 1) {
            if (f < off) red[f] += red[f + off];
            __syncthreads();
        }
        if (f == 0) out[g * DOUTC + o] = red[0] + bc[o];
        __syncthreads();
    }
}

// ---------------------------------------------------------------------------
extern "C" void kernel_launch(void* const* d_in, const int* in_sizes, int n_in,
                              void* d_out, int out_size, void* d_ws, size_t ws_size,
                              hipStream_t stream) {
    const float* x    = (const float*)d_in[0];
    const int*   ei   = (const int*)d_in[1];
    const int*   batch= (const int*)d_in[2];
    const float* W1_0 = (const float*)d_in[3];
    const float* W2_0 = (const float*)d_in[4];
    const float* W1_1 = (const float*)d_in[5];
    const float* W2_1 = (const float*)d_in[6];
    const float* W1_2 = (const float*)d_in[7];
    const float* W2_2 = (const float*)d_in[8];
    const float* Wc   = (const float*)d_in[9];
    const float* bc   = (const float*)d_in[10];
    float* out = (float*)d_out;

    const int* rows = ei;            // edge_index[0] = dst (segment)
    const int* cols = ei + NEDGES;   // edge_index[1] = src (gather)

    // workspace carve-up
    char* ws = (char*)d_ws;
    ushort* Hb = (ushort*)ws;  ws += (size_t)NNODES * DFEAT * sizeof(ushort);
    ushort* Hc = (ushort*)ws;  ws += (size_t)NNODES * DFEAT * sizeof(ushort);
    ushort* Ab = (ushort*)ws;  ws += (size_t)NNODES * DFEAT * sizeof(ushort);
    ushort* Wb = (ushort*)ws;  ws += (size_t)6 * DFEAT * DFEAT * sizeof(ushort);
    float* gsum = (float*)ws;  ws += (size_t)NGRAPH * DFEAT * sizeof(float);
    int* deg    = (int*)ws;    ws += (size_t)NNODES * sizeof(int);
    int* offs   = (int*)ws;    ws += (size_t)(NNODES + 1) * sizeof(int);
    int* cursor = (int*)ws;    ws += (size_t)NNODES * sizeof(int);
    int* scol   = (int*)ws;    ws += (size_t)NEDGES * sizeof(int);
    int* bsum   = (int*)ws;    ws += 128 * sizeof(int);
    int* bbase  = (int*)ws;    ws += 128 * sizeof(int);

    const int NB = (NNODES + 1023) / 1024;

    // dtype conversion
    convert_weights<<<(6 * DFEAT * DFEAT + 255) / 256, 256, 0, stream>>>(
        W1_0, W2_0, W1_1, W2_1, W1_2, W2_2, Wb);
    convert_x_bf16<<<(NNODES * DFEAT / 8 + 255) / 256, 256, 0, stream>>>(x, Hb);

    // CSR build
    hipMemsetAsync(deg, 0, (size_t)NNODES * sizeof(int), stream);
    hipMemsetAsync(gsum, 0, (size_t)NGRAPH * DFEAT * sizeof(float), stream);
    histo_kernel<<<(NEDGES + 255) / 256, 256, 0, stream>>>(rows, deg);
    scan_block_sums<<<NB, 256, 0, stream>>>(deg, bsum);
    scan_bsum<<<1, 128, 0, stream>>>(bsum, bbase, NB);
    scan_write<<<NB, 256, 0, stream>>>(deg, bbase, offs, cursor);
    scatter_edges<<<(NEDGES + 255) / 256, 256, 0, stream>>>(rows, cols, cursor, scol);

    // 3 GNN layers: A = gather(Hcur); Hnext = relu(Hcur@W1^T + A@W2^T)
    const int aggGrid  = ((size_t)NNODES * 64 + 255) / 256;
    const int gemmGrid = 784;
    const ushort* hcur = Hb;
    ushort* hnext = Hc;
    for (int l = 0; l < 3; ++l) {
        const ushort* w1 = Wb + (size_t)(2 * l) * DFEAT * DFEAT;
        const ushort* w2 = Wb + (size_t)(2 * l + 1) * DFEAT * DFEAT;
        aggregate_gather4<<<aggGrid, 256, 0, stream>>>(hcur, offs, scol, Ab);
        fused_dual_gemm<<<gemmGrid, 256, 0, stream>>>(hcur, Ab, w1, w2, hnext);
        const ushort* tmp = hcur; hcur = hnext; hnext = (ushort*)tmp;
    }

    // pooling + classifier (final H is in hcur after the swap)
    const int poolWaves = (NNODES + 63) / 64;
    pool_partial<<<(poolWaves * 64 + 255) / 256, 256, 0, stream>>>(hcur, batch, gsum);
    pool_classify2<<<NGRAPH, 128, 0, stream>>>(gsum, batch, Wc, bc, out);
}

// Round 7
// 324.889 us; speedup vs baseline: 1.1845x; 1.0608x over previous
//
#include <hip/hip_runtime.h>

#define NNODES 100000
#define NEDGES 625000
#define DFEAT  128
#define NGRAPH 256
#define DOUTC  10

typedef __attribute__((ext_vector_type(8))) short bf16x8;
typedef __attribute__((ext_vector_type(4))) float f32x4;
typedef __attribute__((ext_vector_type(8))) ushort ushort8v;

__device__ __forceinline__ ushort f2bf(float f) {
    __bf16 b = (__bf16)f;
    return __builtin_bit_cast(ushort, b);
}
__device__ __forceinline__ float bf2f(ushort u) {
    return __builtin_bit_cast(float, (uint)u << 16);
}

// ---------------------------------------------------------------------------
// CSR build: histogram -> scan -> scatter (counting sort of edges by row)
// ---------------------------------------------------------------------------
__global__ __launch_bounds__(256) void histo_kernel(const int* __restrict__ rows,
                                                    int* __restrict__ deg) {
    int i = blockIdx.x * 256 + threadIdx.x;
    if (i < NEDGES) atomicAdd(&deg[rows[i]], 1);
}

__global__ __launch_bounds__(256) void scan_block_sums(const int* __restrict__ deg,
                                                       int* __restrict__ bsum) {
    __shared__ int red[256];
    int b = blockIdx.x, t = threadIdx.x;
    int base = b * 1024 + t * 4;
    int s = 0;
#pragma unroll
    for (int j = 0; j < 4; ++j) {
        int i = base + j;
        if (i < NNODES) s += deg[i];
    }
    red[t] = s;
    __syncthreads();
    for (int off = 128; off > 0; off >>= 1) {
        if (t < off) red[t] += red[t + off];
        __syncthreads();
    }
    if (t == 0) bsum[b] = red[0];
}

__global__ __launch_bounds__(128) void scan_bsum(const int* __restrict__ bsum,
                                                 int* __restrict__ bbase, int nb) {
    __shared__ int sh[128];
    int t = threadIdx.x;
    sh[t] = (t < nb) ? bsum[t] : 0;
    __syncthreads();
    if (t == 0) {
        int run = 0;
        for (int i = 0; i < nb; ++i) { int v = sh[i]; sh[i] = run; run += v; }
    }
    __syncthreads();
    if (t < nb) bbase[t] = sh[t];
}

__global__ __launch_bounds__(256) void scan_write(const int* __restrict__ deg,
                                                  const int* __restrict__ bbase,
                                                  int* __restrict__ offs,
                                                  int* __restrict__ cursor) {
    __shared__ int red[256];
    int b = blockIdx.x, t = threadIdx.x;
    int base = b * 1024 + t * 4;
    int v[4];
    int s = 0;
#pragma unroll
    for (int j = 0; j < 4; ++j) {
        int i = base + j;
        v[j] = (i < NNODES) ? deg[i] : 0;
        s += v[j];
    }
    red[t] = s;
    __syncthreads();
    int x = s;
    for (int off = 1; off < 256; off <<= 1) {
        int y = (t >= off) ? red[t - off] : 0;
        __syncthreads();
        x += y;
        red[t] = x;
        __syncthreads();
    }
    int pre = bbase[b] + x - s;
#pragma unroll
    for (int j = 0; j < 4; ++j) {
        int i = base + j;
        if (i < NNODES) { offs[i] = pre; cursor[i] = pre; }
        pre += v[j];
    }
    if (b == gridDim.x - 1 && t == 255) offs[NNODES] = bbase[b] + x;
}

__global__ __launch_bounds__(256) void scatter_edges(const int* __restrict__ rows,
                                                     const int* __restrict__ cols,
                                                     int* __restrict__ cursor,
                                                     int* __restrict__ scol) {
    int i = blockIdx.x * 256 + threadIdx.x;
    if (i < NEDGES) {
        int p = atomicAdd(&cursor[rows[i]], 1);
        scol[p] = cols[i];
    }
}

// ---------------------------------------------------------------------------
// dtype conversion
// ---------------------------------------------------------------------------
__global__ __launch_bounds__(256) void convert_x_bf16(const float* __restrict__ src,
                                                      ushort* __restrict__ dst) {
    int i = blockIdx.x * 256 + threadIdx.x;
    const int n8 = NNODES * DFEAT / 8;
    if (i >= n8) return;
    float4 a = *(const float4*)&src[(size_t)i * 8];
    float4 b = *(const float4*)&src[(size_t)i * 8 + 4];
    ushort8v o;
    o[0] = f2bf(a.x); o[1] = f2bf(a.y); o[2] = f2bf(a.z); o[3] = f2bf(a.w);
    o[4] = f2bf(b.x); o[5] = f2bf(b.y); o[6] = f2bf(b.z); o[7] = f2bf(b.w);
    *(ushort8v*)&dst[(size_t)i * 8] = o;
}

__global__ __launch_bounds__(256) void convert_weights(const float* __restrict__ w0,
                                                       const float* __restrict__ w1,
                                                       const float* __restrict__ w2,
                                                       const float* __restrict__ w3,
                                                       const float* __restrict__ w4,
                                                       const float* __restrict__ w5,
                                                       ushort* __restrict__ dst) {
    int i = blockIdx.x * 256 + threadIdx.x;
    if (i >= 6 * DFEAT * DFEAT) return;
    const float* ptrs[6] = {w0, w1, w2, w3, w4, w5};
    int m = i >> 14, j = i & 16383;
    dst[i] = f2bf(ptrs[m][j]);
}

// ---------------------------------------------------------------------------
// Aggregate in H-space: A[n] = sum_{e in CSR[n]} H[scol[e]]
// One 16-lane group per node (4 nodes/wave). Lane l owns features [l*8,l*8+8)
// (16 B); group loops its node's edge list with 2 rows in flight. No
// cross-lane reduction, no idle edge slots. Store = 256 B contiguous.
// ---------------------------------------------------------------------------
__global__ __launch_bounds__(256) void aggregate_g16(const ushort* __restrict__ Hb,
                                                     const int* __restrict__ offs,
                                                     const int* __restrict__ scol,
                                                     ushort* __restrict__ Ab) {
    int node = blockIdx.x * 16 + (threadIdx.x >> 4);
    int l = threadIdx.x & 15;
    if (node >= NNODES) return;
    int beg = offs[node];
    int end = offs[node + 1];
    float a[8] = {};
    int e = beg;
    for (; e + 2 <= end; e += 2) {
        int c0 = scol[e];
        int c1 = scol[e + 1];
        ushort8v v0 = *(const ushort8v*)&Hb[(size_t)c0 * DFEAT + l * 8];
        ushort8v v1 = *(const ushort8v*)&Hb[(size_t)c1 * DFEAT + l * 8];
#pragma unroll
        for (int j = 0; j < 8; ++j) a[j] += bf2f(v0[j]) + bf2f(v1[j]);
    }
    if (e < end) {
        int c0 = scol[e];
        ushort8v v0 = *(const ushort8v*)&Hb[(size_t)c0 * DFEAT + l * 8];
#pragma unroll
        for (int j = 0; j < 8; ++j) a[j] += bf2f(v0[j]);
    }
    ushort8v o;
#pragma unroll
    for (int j = 0; j < 8; ++j) o[j] = f2bf(a[j]);
    *(ushort8v*)&Ab[(size_t)node * DFEAT + l * 8] = o;
}

// ---------------------------------------------------------------------------
// Fused layer GEMM: H' = relu(H @ W1^T + A @ W2^T)  (bf16 in/out, f32 acc).
// Wave handles out-half (wid&1): holds W1,W2 fragments for 64 out-features
// (128 VGPR). Teams of 2 waves share each 16-node tile (L1/L2 locality).
// Both matmuls accumulate into the SAME MFMA accumulator.
// ---------------------------------------------------------------------------
__global__ __launch_bounds__(256, 2) void fused_dual_gemm(const ushort* __restrict__ Hin,
                                                          const ushort* __restrict__ Ab,
                                                          const ushort* __restrict__ W1b,
                                                          const ushort* __restrict__ W2b,
                                                          ushort* __restrict__ Hout) {
    int wid = threadIdx.x >> 6;
    int lane = threadIdx.x & 63;
    int l15 = lane & 15, lhi = lane >> 4;
    int half = wid & 1;

    bf16x8 w1[4][4], w2[4][4];
#pragma unroll
    for (int ot = 0; ot < 4; ++ot)
#pragma unroll
        for (int ks = 0; ks < 4; ++ks) {
            int orow = half * 64 + ot * 16 + l15;
            w1[ot][ks] = *(const bf16x8*)&W1b[orow * DFEAT + ks * 32 + lhi * 8];
            w2[ot][ks] = *(const bf16x8*)&W2b[orow * DFEAT + ks * 32 + lhi * 8];
        }

    int team = blockIdx.x * 2 + (wid >> 1);
    const int nteams = gridDim.x * 2;
    const int ntiles = NNODES / 16;              // 6250 exactly

    for (int t = team; t < ntiles; t += nteams) {
        size_t rowOff = (size_t)(t * 16 + l15) * DFEAT;
        bf16x8 hfr[4], afr[4];
#pragma unroll
        for (int ks = 0; ks < 4; ++ks) {
            hfr[ks] = *(const bf16x8*)&Hin[rowOff + ks * 32 + lhi * 8];
            afr[ks] = *(const bf16x8*)&Ab[rowOff + ks * 32 + lhi * 8];
        }
#pragma unroll
        for (int ot = 0; ot < 4; ++ot) {
            f32x4 acc = {};
#pragma unroll
            for (int ks = 0; ks < 4; ++ks)
                acc = __builtin_amdgcn_mfma_f32_16x16x32_bf16(w1[ot][ks], hfr[ks], acc, 0, 0, 0);
#pragma unroll
            for (int ks = 0; ks < 4; ++ks)
                acc = __builtin_amdgcn_mfma_f32_16x16x32_bf16(w2[ot][ks], afr[ks], acc, 0, 0, 0);
            ushort4 p;
            p.x = f2bf(fmaxf(acc.x, 0.f));
            p.y = f2bf(fmaxf(acc.y, 0.f));
            p.z = f2bf(fmaxf(acc.z, 0.f));
            p.w = f2bf(fmaxf(acc.w, 0.f));
            *(ushort4*)&Hout[rowOff + half * 64 + ot * 16 + lhi * 4] = p;
        }
    }
}

// ---------------------------------------------------------------------------
// Pooling phase 1: per-graph feature sums (run-accumulate over sorted batch).
// ---------------------------------------------------------------------------
__global__ __launch_bounds__(256) void pool_partial(const ushort* __restrict__ Hb,
                                                    const int* __restrict__ batch,
                                                    float* __restrict__ gsum) {
    int wave = (blockIdx.x * 256 + threadIdx.x) >> 6;
    int lane = threadIdx.x & 63;
    int base = wave * 64;
    if (base >= NNODES) return;
    int end = min(base + 64, NNODES);
    const uint* Hp = (const uint*)Hb + lane;
    float ax = 0.f, ay = 0.f;
    int gprev = batch[base];
    for (int n = base; n < end; ++n) {
        int g = batch[n];
        if (g != gprev) {
            atomicAdd(&gsum[gprev * DFEAT + lane * 2], ax);
            atomicAdd(&gsum[gprev * DFEAT + lane * 2 + 1], ay);
            ax = 0.f; ay = 0.f; gprev = g;
        }
        uint v = Hp[(size_t)n * 64];
        ax += __builtin_bit_cast(float, v << 16);
        ay += __builtin_bit_cast(float, v & 0xffff0000u);
    }
    atomicAdd(&gsum[gprev * DFEAT + lane * 2], ax);
    atomicAdd(&gsum[gprev * DFEAT + lane * 2 + 1], ay);
}

// ---------------------------------------------------------------------------
// Pooling phase 2: divide by count, classify.
// ---------------------------------------------------------------------------
__global__ __launch_bounds__(128) void pool_classify2(const float* __restrict__ gsum,
                                                      const int* __restrict__ batch,
                                                      const float* __restrict__ Wc,
                                                      const float* __restrict__ bc,
                                                      float* __restrict__ out) {
    int g = blockIdx.x;
    int f = threadIdx.x;
    __shared__ int bounds[2];
    if (f < 2) {
        int target = g + f;
        int lo = 0, hi = NNODES;
        while (lo < hi) {
            int mid = (lo + hi) >> 1;
            if (batch[mid] < target) lo = mid + 1; else hi = mid;
        }
        bounds[f] = lo;
    }
    __syncthreads();
    float cnt = (float)(bounds[1] - bounds[0]);
    float pooled = gsum[g * DFEAT + f] / fmaxf(cnt, 1.0f);

    __shared__ float red[128];
    for (int o = 0; o < DOUTC; ++o) {
        red[f] = pooled * Wc[o * DFEAT + f];
        __syncthreads();
        for (int off = 64; off > 0; off >>= 1) {
            if (f < off) red[f] += red[f + off];
            __syncthreads();
        }
        if (f == 0) out[g * DOUTC + o] = red[0] + bc[o];
        __syncthreads();
    }
}

// ---------------------------------------------------------------------------
extern "C" void kernel_launch(void* const* d_in, const int* in_sizes, int n_in,
                              void* d_out, int out_size, void* d_ws, size_t ws_size,
                              hipStream_t stream) {
    const float* x    = (const float*)d_in[0];
    const int*   ei   = (const int*)d_in[1];
    const int*   batch= (const int*)d_in[2];
    const float* W1_0 = (const float*)d_in[3];
    const float* W2_0 = (const float*)d_in[4];
    const float* W1_1 = (const float*)d_in[5];
    const float* W2_1 = (const float*)d_in[6];
    const float* W1_2 = (const float*)d_in[7];
    const float* W2_2 = (const float*)d_in[8];
    const float* Wc   = (const float*)d_in[9];
    const float* bc   = (const float*)d_in[10];
    float* out = (float*)d_out;

    const int* rows = ei;            // edge_index[0] = dst (segment)
    const int* cols = ei + NEDGES;   // edge_index[1] = src (gather)

    // workspace carve-up
    char* ws = (char*)d_ws;
    ushort* Hb = (ushort*)ws;  ws += (size_t)NNODES * DFEAT * sizeof(ushort);
    ushort* Hc = (ushort*)ws;  ws += (size_t)NNODES * DFEAT * sizeof(ushort);
    ushort* Ab = (ushort*)ws;  ws += (size_t)NNODES * DFEAT * sizeof(ushort);
    ushort* Wb = (ushort*)ws;  ws += (size_t)6 * DFEAT * DFEAT * sizeof(ushort);
    float* gsum = (float*)ws;  ws += (size_t)NGRAPH * DFEAT * sizeof(float);
    int* deg    = (int*)ws;    ws += (size_t)NNODES * sizeof(int);
    int* offs   = (int*)ws;    ws += (size_t)(NNODES + 1) * sizeof(int);
    int* cursor = (int*)ws;    ws += (size_t)NNODES * sizeof(int);
    int* scol   = (int*)ws;    ws += (size_t)NEDGES * sizeof(int);
    int* bsum   = (int*)ws;    ws += 128 * sizeof(int);
    int* bbase  = (int*)ws;    ws += 128 * sizeof(int);

    const int NB = (NNODES + 1023) / 1024;

    // dtype conversion
    convert_weights<<<(6 * DFEAT * DFEAT + 255) / 256, 256, 0, stream>>>(
        W1_0, W2_0, W1_1, W2_1, W1_2, W2_2, Wb);
    convert_x_bf16<<<(NNODES * DFEAT / 8 + 255) / 256, 256, 0, stream>>>(x, Hb);

    // CSR build
    hipMemsetAsync(deg, 0, (size_t)NNODES * sizeof(int), stream);
    hipMemsetAsync(gsum, 0, (size_t)NGRAPH * DFEAT * sizeof(float), stream);
    histo_kernel<<<(NEDGES + 255) / 256, 256, 0, stream>>>(rows, deg);
    scan_block_sums<<<NB, 256, 0, stream>>>(deg, bsum);
    scan_bsum<<<1, 128, 0, stream>>>(bsum, bbase, NB);
    scan_write<<<NB, 256, 0, stream>>>(deg, bbase, offs, cursor);
    scatter_edges<<<(NEDGES + 255) / 256, 256, 0, stream>>>(rows, cols, cursor, scol);

    // 3 GNN layers: A = gather(Hcur); Hnext = relu(Hcur@W1^T + A@W2^T)
    const int aggGrid  = (NNODES + 15) / 16;         // 16 nodes per 256-thr block
    const int gemmGrid = 784;
    const ushort* hcur = Hb;
    ushort* hnext = Hc;
    for (int l = 0; l < 3; ++l) {
        const ushort* w1 = Wb + (size_t)(2 * l) * DFEAT * DFEAT;
        const ushort* w2 = Wb + (size_t)(2 * l + 1) * DFEAT * DFEAT;
        aggregate_g16<<<aggGrid, 256, 0, stream>>>(hcur, offs, scol, Ab);
        fused_dual_gemm<<<gemmGrid, 256, 0, stream>>>(hcur, Ab, w1, w2, hnext);
        const ushort* tmp = hcur; hcur = hnext; hnext = (ushort*)tmp;
    }

    // pooling + classifier (final H is in hcur after the swap)
    const int poolWaves = (NNODES + 63) / 64;
    pool_partial<<<(poolWaves * 64 + 255) / 256, 256, 0, stream>>>(hcur, batch, gsum);
    pool_classify2<<<NGRAPH, 128, 0, stream>>>(gsum, batch, Wc, bc, out);
}